// Round 1
// baseline (508.267 us; speedup 1.0000x reference)
//
#include <hip/hip_runtime.h>
#include <math.h>

#define STATE_DIM 168
#define BTOT 65536

// Skewed hp layout: c in [0,128), n in [0,8). pitch 9 + per-head skew 8
// -> hp writes 2-way, e_i/e_j reads conflict-free, graphs reads 2-way.
__device__ __forceinline__ int hp_off(int c, int n) {
    return c * 9 + ((c >> 5) << 3) + n;
}

// ---------------- Kernel A: hyper-net FFN ----------------
// 1 wave per 8 samples. Computes w_final (B x 8) and w_dvd (B x 128) into ws.
__global__ void __launch_bounds__(256)
ffn_kernel(const float* __restrict__ states,
           const float* __restrict__ w1f, const float* __restrict__ b1f,
           const float* __restrict__ w2f, const float* __restrict__ b2f,
           const float* __restrict__ Wd,  const float* __restrict__ bd,
           float* __restrict__ wfin, float* __restrict__ wdvd)
{
    __shared__ float S_lds[4][8 * STATE_DIM];   // 5376 B / wave
    __shared__ float y1_lds[4][8 * 65];         // pitch 65: conflict-free phase 3

    const int wid  = threadIdx.x >> 6;
    const int lane = threadIdx.x & 63;
    const int wgi  = blockIdx.x * 4 + wid;      // 0..8191
    const long s0  = (long)wgi * 8;

    // stage S: 8 samples x 168 = 1344 floats, contiguous, coalesced
    const float* Sg = states + s0 * STATE_DIM;
    float* Sl = S_lds[wid];
    #pragma unroll
    for (int i = 0; i < 21; ++i)
        Sl[lane + i * 64] = Sg[lane + i * 64];
    __syncthreads();

    // lane owns: y1 column `lane` (w1f), w_dvd columns lane and lane+64 (Wd)
    float acc1[8], ad0[8], ad1[8];
    const float bb1  = b1f[lane];
    const float bdv0 = bd[lane];
    const float bdv1 = bd[lane + 64];
    #pragma unroll
    for (int s = 0; s < 8; ++s) { acc1[s] = bb1; ad0[s] = bdv0; ad1[s] = bdv1; }

    for (int k = 0; k < STATE_DIM; k += 4) {
        float w1[4], wd0[4], wd1[4];
        #pragma unroll
        for (int kk = 0; kk < 4; ++kk) {
            w1[kk]  = w1f[(k + kk) * 64 + lane];
            wd0[kk] = Wd[(k + kk) * 128 + lane];
            wd1[kk] = Wd[(k + kk) * 128 + 64 + lane];
        }
        #pragma unroll
        for (int s = 0; s < 8; ++s) {
            const float4 sv = *(const float4*)&Sl[s * STATE_DIM + k];  // broadcast b128
            acc1[s] = fmaf(sv.x, w1[0], acc1[s]);
            acc1[s] = fmaf(sv.y, w1[1], acc1[s]);
            acc1[s] = fmaf(sv.z, w1[2], acc1[s]);
            acc1[s] = fmaf(sv.w, w1[3], acc1[s]);
            ad0[s] = fmaf(sv.x, wd0[0], ad0[s]);
            ad0[s] = fmaf(sv.y, wd0[1], ad0[s]);
            ad0[s] = fmaf(sv.z, wd0[2], ad0[s]);
            ad0[s] = fmaf(sv.w, wd0[3], ad0[s]);
            ad1[s] = fmaf(sv.x, wd1[0], ad1[s]);
            ad1[s] = fmaf(sv.y, wd1[1], ad1[s]);
            ad1[s] = fmaf(sv.z, wd1[2], ad1[s]);
            ad1[s] = fmaf(sv.w, wd1[3], ad1[s]);
        }
    }

    #pragma unroll
    for (int s = 0; s < 8; ++s) {
        y1_lds[wid][s * 65 + lane] = fmaxf(acc1[s], 0.0f);
        wdvd[(s0 + s) * 128 + lane]      = ad0[s];   // coalesced
        wdvd[(s0 + s) * 128 + 64 + lane] = ad1[s];
    }
    __syncthreads();

    // second layer: lane -> (s = lane>>3, n = lane&7)
    {
        const int s = lane >> 3, n = lane & 7;
        float acc = b2f[n];
        #pragma unroll
        for (int j = 0; j < 64; ++j)
            acc = fmaf(y1_lds[wid][s * 65 + j], w2f[j * 8 + n], acc);
        wfin[(s0 + s) * 8 + n] = fabsf(acc) + 1e-10f;
    }
}

// ---------------- Kernel B: GAT + mixing ----------------
// block = 4 waves; Wg + att_a staged once; each wave loops 8 samples.
__global__ void __launch_bounds__(256)
gat_kernel(const float* __restrict__ agent_qs,
           const float* __restrict__ max_q_i,
           const float* __restrict__ hidden,
           const float* __restrict__ Wg,
           const float* __restrict__ att_a,
           const float* __restrict__ wfin,
           const float* __restrict__ wdvd,
           float* __restrict__ out)
{
    __shared__ float Wg_lds[64 * 128];   // 32 KB
    __shared__ float a_lds[8 * 33];      // [h*2+which][33] padded: conflict-free
    __shared__ float Hl[4][512];
    __shared__ float hp_lds[4][1176];    // skewed (hp_off)
    __shared__ float ei_lds[4][32];
    __shared__ float ej_lds[4][32];
    __shared__ float attn_lds[4][256];   // [h][i][j]
    __shared__ float wd_lds[4][128];
    __shared__ float ws_lds[4][32];      // |wd . g| per (h,n)

    const int wid  = threadIdx.x >> 6;
    const int lane = threadIdx.x & 63;
    const int t    = threadIdx.x;

    #pragma unroll
    for (int i = 0; i < 32; ++i)
        Wg_lds[t + i * 256] = Wg[t + i * 256];
    {
        const int h = t >> 6, r = t & 63, wch = r >> 5, d = r & 31;
        a_lds[(h * 2 + wch) * 33 + d] = att_a[t];
    }
    __syncthreads();

    const int wgid = blockIdx.x * 4 + wid;   // 0..8191

    for (int it = 0; it < 8; ++it) {
        const long smp = wgid + (long)it * 8192;

        // stage H (2 KB) + w_dvd (512 B)
        const float* Hg = hidden + smp * 512;
        #pragma unroll
        for (int i = 0; i < 8; ++i)
            Hl[wid][lane + i * 64] = Hg[lane + i * 64];
        wd_lds[wid][lane]      = wdvd[smp * 128 + lane];
        wd_lds[wid][lane + 64] = wdvd[smp * 128 + 64 + lane];
        __syncthreads();

        // hp[c][n] = sum_k H[n][k] * Wg[k][c];  lane owns c = lane, lane+64
        {
            float a0[8], a1[8];
            #pragma unroll
            for (int n = 0; n < 8; ++n) { a0[n] = 0.f; a1[n] = 0.f; }
            for (int k = 0; k < 64; k += 4) {
                float g0[4], g1[4];
                #pragma unroll
                for (int kk = 0; kk < 4; ++kk) {
                    g0[kk] = Wg_lds[(k + kk) * 128 + lane];        // 2-way: free
                    g1[kk] = Wg_lds[(k + kk) * 128 + 64 + lane];
                }
                #pragma unroll
                for (int n = 0; n < 8; ++n) {
                    const float4 hv = *(const float4*)&Hl[wid][n * 64 + k]; // broadcast
                    a0[n] = fmaf(hv.x, g0[0], a0[n]);
                    a0[n] = fmaf(hv.y, g0[1], a0[n]);
                    a0[n] = fmaf(hv.z, g0[2], a0[n]);
                    a0[n] = fmaf(hv.w, g0[3], a0[n]);
                    a1[n] = fmaf(hv.x, g1[0], a1[n]);
                    a1[n] = fmaf(hv.y, g1[1], a1[n]);
                    a1[n] = fmaf(hv.z, g1[2], a1[n]);
                    a1[n] = fmaf(hv.w, g1[3], a1[n]);
                }
            }
            #pragma unroll
            for (int n = 0; n < 8; ++n) {
                hp_lds[wid][hp_off(lane, n)]      = a0[n];
                hp_lds[wid][hp_off(lane + 64, n)] = a1[n];
            }
        }
        __syncthreads();

        // e_i / e_j: lane -> (h = lane>>4, which = (lane>>3)&1, n = lane&7)
        {
            const int h = lane >> 4, r = lane & 15, wch = r >> 3, n = r & 7;
            const float* arow = &a_lds[(h * 2 + wch) * 33];
            float acc = 0.f;
            #pragma unroll
            for (int d = 0; d < 32; ++d)
                acc = fmaf(hp_lds[wid][hp_off(h * 32 + d, n)], arow[d], acc);
            if (wch) ej_lds[wid][h * 8 + n] = acc;
            else     ei_lds[wid][h * 8 + n] = acc;
        }
        __syncthreads();

        // leaky-relu + softmax over j: lanes 0..31 -> (h, i)
        if (lane < 32) {
            const int h = lane >> 3, i = lane & 7;
            const float eiv = ei_lds[wid][h * 8 + i];
            float e[8], mx = -1e30f;
            #pragma unroll
            for (int j = 0; j < 8; ++j) {
                float v = eiv + ej_lds[wid][h * 8 + j];
                v = v > 0.f ? v : 0.2f * v;
                e[j] = v;
                mx = fmaxf(mx, v);
            }
            float ssum = 0.f;
            #pragma unroll
            for (int j = 0; j < 8; ++j) { e[j] = __expf(e[j] - mx); ssum += e[j]; }
            const float inv = 1.f / ssum;
            #pragma unroll
            for (int j = 0; j < 8; ++j)
                attn_lds[wid][h * 64 + i * 8 + j] = e[j] * inv;
        }
        __syncthreads();

        // graphs = elu(attn @ hp); |sum_d wd[h,d]*g[h,n,d]|
        // lane -> (h,n) pair, d split in halves of 16
        {
            const int pr = lane >> 1, dh = lane & 1;
            const int h = pr >> 3, n = pr & 7;
            float arow[8];
            #pragma unroll
            for (int j = 0; j < 8; ++j)
                arow[j] = attn_lds[wid][h * 64 + n * 8 + j];
            float part = 0.f;
            #pragma unroll
            for (int dd = 0; dd < 16; ++dd) {
                const int c = h * 32 + dh * 16 + dd;
                float g = 0.f;
                #pragma unroll
                for (int j = 0; j < 8; ++j)
                    g = fmaf(arow[j], hp_lds[wid][hp_off(c, j)], g);
                g = g > 0.f ? g : (__expf(g) - 1.0f);       // elu
                part = fmaf(wd_lds[wid][c], g, part);
            }
            part += __shfl_xor(part, 1, 64);                 // combine d-halves
            if (dh == 0) ws_lds[wid][h * 8 + n] = fabsf(part);
        }
        __syncthreads();

        // adv_w_final = mean_h; adv_tot = sum_n w_final*(q-mq)*(awf-1)
        if (lane < 8) {
            const int n = lane;
            const float awf = 0.25f * (ws_lds[wid][n] + ws_lds[wid][8 + n] +
                                       ws_lds[wid][16 + n] + ws_lds[wid][24 + n]);
            const float adv = wfin[smp * 8 + n] *
                              (agent_qs[smp * 8 + n] - max_q_i[smp * 8 + n]);
            float p = adv * (awf - 1.0f);
            p += __shfl_xor(p, 4, 64);   // xor stays inside active lanes 0..7
            p += __shfl_xor(p, 2, 64);
            p += __shfl_xor(p, 1, 64);
            if (n == 0) out[smp] = p;
        }
        __syncthreads();
    }
}

extern "C" void kernel_launch(void* const* d_in, const int* in_sizes, int n_in,
                              void* d_out, int out_size, void* d_ws, size_t ws_size,
                              hipStream_t stream) {
    const float* agent_qs = (const float*)d_in[0];
    const float* states   = (const float*)d_in[1];
    const float* max_q_i  = (const float*)d_in[2];
    const float* hidden   = (const float*)d_in[3];
    const float* w1f = (const float*)d_in[4];
    const float* b1f = (const float*)d_in[5];
    const float* w2f = (const float*)d_in[6];
    const float* b2f = (const float*)d_in[7];
    // d_in[8..11] = w1v,b1v,w2v,b2v: v cancels in adv_q = q - mq, unused.
    const float* Wg    = (const float*)d_in[12];
    const float* att_a = (const float*)d_in[13];
    const float* Wd    = (const float*)d_in[14];
    const float* bd    = (const float*)d_in[15];
    float* out  = (float*)d_out;

    float* wfin = (float*)d_ws;                    // [BTOT][8]
    float* wdvd = wfin + (size_t)BTOT * 8;         // [BTOT][128]  (total 35.7 MB)

    ffn_kernel<<<2048, 256, 0, stream>>>(states, w1f, b1f, w2f, b2f, Wd, bd,
                                         wfin, wdvd);
    gat_kernel<<<2048, 256, 0, stream>>>(agent_qs, max_q_i, hidden, Wg, att_a,
                                         wfin, wdvd, out);
}

// Round 3
// 364.277 us; speedup vs baseline: 1.3953x; 1.3953x over previous
//
#include <hip/hip_runtime.h>
#include <math.h>

#define STATE_DIM 168
#define BTOT 65536
#define SLS 1064   // per-sample hp stride (floats); %32==8 -> bank-spreads sl

typedef float f32x4 __attribute__((ext_vector_type(4)));
typedef short bf16x8 __attribute__((ext_vector_type(8)));

union Frag { bf16x8 v; unsigned short u[8]; };
union Acc  { f32x4 v; float f[4]; };

__device__ __forceinline__ unsigned short f2bf(float f) {
    unsigned int u = __float_as_uint(f);
    u += 0x7fffu + ((u >> 16) & 1u);          // round-to-nearest-even
    return (unsigned short)(u >> 16);
}

// ---------------- Kernel A: hyper-net FFN (fp32 VALU, pipelined weights) ----
__global__ void __launch_bounds__(256, 5)
ffn_kernel(const float* __restrict__ states,
           const float* __restrict__ w1f, const float* __restrict__ b1f,
           const float* __restrict__ w2f, const float* __restrict__ b2f,
           const float* __restrict__ Wd,  const float* __restrict__ bd,
           float* __restrict__ wfin, float* __restrict__ wdvd)
{
    __shared__ float S_lds[4][8 * STATE_DIM];
    __shared__ float y1_lds[4][8 * 65];

    const int wid  = threadIdx.x >> 6;
    const int lane = threadIdx.x & 63;
    const int wgi  = blockIdx.x * 4 + wid;
    const long s0  = (long)wgi * 8;

    const float* Sg = states + s0 * STATE_DIM;
    float* Sl = S_lds[wid];
    #pragma unroll
    for (int i = 0; i < 21; ++i)
        Sl[lane + i * 64] = Sg[lane + i * 64];
    __syncthreads();

    float acc1[8], ad0[8], ad1[8];
    const float bb1  = b1f[lane];
    const float bdv0 = bd[lane];
    const float bdv1 = bd[lane + 64];
    #pragma unroll
    for (int s = 0; s < 8; ++s) { acc1[s] = bb1; ad0[s] = bdv0; ad1[s] = bdv1; }

    // prefetch chunk 0
    float w1c[4], wd0c[4], wd1c[4];
    #pragma unroll
    for (int kk = 0; kk < 4; ++kk) {
        w1c[kk]  = w1f[kk * 64 + lane];
        wd0c[kk] = Wd[kk * 128 + lane];
        wd1c[kk] = Wd[kk * 128 + 64 + lane];
    }

    for (int k = 0; k < STATE_DIM; k += 4) {
        // prefetch next chunk's weights while computing current
        const int kn = (k + 4 < STATE_DIM) ? (k + 4) : k;
        float w1n[4], wd0n[4], wd1n[4];
        #pragma unroll
        for (int kk = 0; kk < 4; ++kk) {
            w1n[kk]  = w1f[(kn + kk) * 64 + lane];
            wd0n[kk] = Wd[(kn + kk) * 128 + lane];
            wd1n[kk] = Wd[(kn + kk) * 128 + 64 + lane];
        }
        #pragma unroll
        for (int s = 0; s < 8; ++s) {
            const float4 sv = *(const float4*)&Sl[s * STATE_DIM + k];
            acc1[s] = fmaf(sv.x, w1c[0], acc1[s]);
            acc1[s] = fmaf(sv.y, w1c[1], acc1[s]);
            acc1[s] = fmaf(sv.z, w1c[2], acc1[s]);
            acc1[s] = fmaf(sv.w, w1c[3], acc1[s]);
            ad0[s] = fmaf(sv.x, wd0c[0], ad0[s]);
            ad0[s] = fmaf(sv.y, wd0c[1], ad0[s]);
            ad0[s] = fmaf(sv.z, wd0c[2], ad0[s]);
            ad0[s] = fmaf(sv.w, wd0c[3], ad0[s]);
            ad1[s] = fmaf(sv.x, wd1c[0], ad1[s]);
            ad1[s] = fmaf(sv.y, wd1c[1], ad1[s]);
            ad1[s] = fmaf(sv.z, wd1c[2], ad1[s]);
            ad1[s] = fmaf(sv.w, wd1c[3], ad1[s]);
        }
        #pragma unroll
        for (int kk = 0; kk < 4; ++kk) {
            w1c[kk] = w1n[kk]; wd0c[kk] = wd0n[kk]; wd1c[kk] = wd1n[kk];
        }
    }

    #pragma unroll
    for (int s = 0; s < 8; ++s) {
        y1_lds[wid][s * 65 + lane] = fmaxf(acc1[s], 0.0f);
        wdvd[(s0 + s) * 128 + lane]      = ad0[s];
        wdvd[(s0 + s) * 128 + 64 + lane] = ad1[s];
    }
    __syncthreads();

    {
        const int s = lane >> 3, n = lane & 7;
        float acc = b2f[n];
        #pragma unroll
        for (int j = 0; j < 64; ++j)
            acc = fmaf(y1_lds[wid][s * 65 + j], w2f[j * 8 + n], acc);
        wfin[(s0 + s) * 8 + n] = fabsf(acc) + 1e-10f;
    }
}

// ---------------- Kernel B: GAT via MFMA, barrier-free per-wave --------------
// Each wave owns 8 CONTIGUOUS samples (wgid*8 .. wgid*8+7), processed as
// 4 groups of 2. hp = H @ Wg via mfma 16x16x32 bf16:
//   M=16 (2 samples x 8 agents), N=128 (8 tiles), K=64 (2 ksteps).
// B-fragments (Wg) are wave-invariant -> hoisted into 64 VGPRs.
// hp layout in LDS: addr = sl*SLS + c*8 + 8*(c>>5) + n
__global__ void __launch_bounds__(256, 3)
gat_kernel(const float* __restrict__ agent_qs,
           const float* __restrict__ max_q_i,
           const float* __restrict__ hidden,
           const float* __restrict__ Wg,
           const float* __restrict__ att_a,
           const float* __restrict__ wfin,
           const float* __restrict__ wdvd,
           float* __restrict__ out)
{
    __shared__ float hp_lds[4][2 * SLS];   // 2 samples, skewed
    __shared__ float attn_lds[4][544];     // [sl*272 + h*66 + i*8 + j]
    __shared__ float e_lds[4][128];        // [sl*64 + wch*32 + h*8 + n]
    __shared__ float ws_lds[4][64];        // [sl*32 + h*8 + n]
    __shared__ float a_lds[264];           // [(h*2+wch)*33 + d]

    const int t    = threadIdx.x;
    const int wid  = t >> 6;
    const int lane = t & 63;

    {   // one-time stage of att_a (256 floats), padded
        const int h = t >> 6, r = t & 63, wch = r >> 5, d = r & 31;
        a_lds[(h * 2 + wch) * 33 + d] = att_a[t];
    }
    __syncthreads();   // the ONLY barrier

    float* hp  = hp_lds[wid];
    float* at  = attn_lds[wid];
    float* el  = e_lds[wid];
    float* wsl = ws_lds[wid];

    const int wgid = blockIdx.x * 4 + wid;   // 0..8191, owns samples wgid*8..+7
    const int quad = lane >> 4;
    const int col  = lane & 15;

    // ---- hoist all B fragments (Wg, bf16) into registers: 16 x ushort8 ----
    // B[k = ks*32 + quad*8 + j][n = tt*16 + col]
    Frag Bf[8][2];
    #pragma unroll
    for (int tt = 0; tt < 8; ++tt)
        #pragma unroll
        for (int ks = 0; ks < 2; ++ks)
            #pragma unroll
            for (int j = 0; j < 8; ++j)
                Bf[tt][ks].u[j] =
                    f2bf(Wg[(ks * 32 + quad * 8 + j) * 128 + tt * 16 + col]);

    const int sl_a = (lane >> 3) & 1;   // A-frag: which of the 2 samples
    const int n_a  = lane & 7;          // agent row
    const int sl_w = quad >> 1;         // C-frag: sample of this quad
    const int nb   = (quad & 1) * 4;    // C-frag: first agent of this quad

    for (int g = 0; g < 4; ++g) {
        const long smp0 = (long)wgid * 8 + 2 * g;   // bijective coverage

        // ---- A fragments: H rows, fp32 -> bf16. A[m=lane&15][k=quad*8+j] ----
        Frag A0, A1;
        {
            const float* Hb = hidden + (smp0 + sl_a) * 512 + n_a * 64 + quad * 8;
            const float4 h00 = *(const float4*)(Hb);
            const float4 h01 = *(const float4*)(Hb + 4);
            const float4 h10 = *(const float4*)(Hb + 32);
            const float4 h11 = *(const float4*)(Hb + 36);
            A0.u[0] = f2bf(h00.x); A0.u[1] = f2bf(h00.y);
            A0.u[2] = f2bf(h00.z); A0.u[3] = f2bf(h00.w);
            A0.u[4] = f2bf(h01.x); A0.u[5] = f2bf(h01.y);
            A0.u[6] = f2bf(h01.z); A0.u[7] = f2bf(h01.w);
            A1.u[0] = f2bf(h10.x); A1.u[1] = f2bf(h10.y);
            A1.u[2] = f2bf(h10.z); A1.u[3] = f2bf(h10.w);
            A1.u[4] = f2bf(h11.x); A1.u[5] = f2bf(h11.y);
            A1.u[6] = f2bf(h11.z); A1.u[7] = f2bf(h11.w);
        }

        // ---- MFMA: 8 tiles x 2 ksteps; store hp to LDS in C-layout ----
        // D row m = quad*4 + reg -> sample sl_w = m>>3, agent = nb + reg
        #pragma unroll
        for (int tt = 0; tt < 8; ++tt) {
            Acc acc;
            acc.v = (f32x4){0.f, 0.f, 0.f, 0.f};
            acc.v = __builtin_amdgcn_mfma_f32_16x16x32_bf16(A0.v, Bf[tt][0].v, acc.v, 0, 0, 0);
            acc.v = __builtin_amdgcn_mfma_f32_16x16x32_bf16(A1.v, Bf[tt][1].v, acc.v, 0, 0, 0);
            const int c = tt * 16 + col;
            float4 st = {acc.f[0], acc.f[1], acc.f[2], acc.f[3]};  // n = nb..nb+3
            *(float4*)&hp[sl_w * SLS + c * 8 + ((c >> 5) << 3) + nb] = st;
        }

        // ---- e_i / e_j ----
        {
            const int h = lane >> 4, r = lane & 15, wch = r >> 3, n = r & 7;
            const float* arow = &a_lds[(h * 2 + wch) * 33];
            #pragma unroll
            for (int sl = 0; sl < 2; ++sl) {
                float acc = 0.f;
                #pragma unroll
                for (int d = 0; d < 32; ++d)
                    acc = fmaf(hp[sl * SLS + (h * 32 + d) * 8 + h * 8 + n],
                               arow[d], acc);
                el[sl * 64 + wch * 32 + h * 8 + n] = acc;
            }
        }

        // ---- leaky-relu + softmax (both samples at once) ----
        {
            const int sl = lane >> 5, r = lane & 31, h = r >> 3, i = r & 7;
            const float eiv = el[sl * 64 + h * 8 + i];
            const float* ejp = &el[sl * 64 + 32 + h * 8];
            float e[8], mx = -1e30f;
            #pragma unroll
            for (int j = 0; j < 8; ++j) {
                float v = eiv + ejp[j];
                v = v > 0.f ? v : 0.2f * v;
                e[j] = v;
                mx = fmaxf(mx, v);
            }
            float ssum = 0.f;
            #pragma unroll
            for (int j = 0; j < 8; ++j) { e[j] = __expf(e[j] - mx); ssum += e[j]; }
            const float inv = 1.f / ssum;
            #pragma unroll
            for (int j = 0; j < 8; ++j)
                at[sl * 272 + h * 66 + i * 8 + j] = e[j] * inv;
        }

        // ---- graphs = elu(attn @ hp); ws[h][n] = |sum_d wd[h,d]*g[n,d]| ----
        {
            const int sl = lane >> 5, r = lane & 31, h = r >> 3, n = r & 7;
            const long smp = smp0 + sl;
            float ar[8];
            #pragma unroll
            for (int j = 0; j < 8; ++j)
                ar[j] = at[sl * 272 + h * 66 + n * 8 + j];
            float wdd[32];
            {
                const float* wdp = wdvd + smp * 128 + h * 32;
                #pragma unroll
                for (int q4 = 0; q4 < 8; ++q4) {
                    const float4 v = *(const float4*)(wdp + q4 * 4);
                    wdd[q4 * 4 + 0] = v.x; wdd[q4 * 4 + 1] = v.y;
                    wdd[q4 * 4 + 2] = v.z; wdd[q4 * 4 + 3] = v.w;
                }
            }
            float part = 0.f;
            #pragma unroll
            for (int d = 0; d < 32; ++d) {
                const int c = h * 32 + d;
                const float* hb = &hp[sl * SLS + c * 8 + h * 8];
                const float4 p0 = *(const float4*)(hb);
                const float4 p1 = *(const float4*)(hb + 4);
                float gg = ar[0] * p0.x;
                gg = fmaf(ar[1], p0.y, gg);
                gg = fmaf(ar[2], p0.z, gg);
                gg = fmaf(ar[3], p0.w, gg);
                gg = fmaf(ar[4], p1.x, gg);
                gg = fmaf(ar[5], p1.y, gg);
                gg = fmaf(ar[6], p1.z, gg);
                gg = fmaf(ar[7], p1.w, gg);
                gg = gg > 0.f ? gg : (__expf(gg) - 1.0f);   // elu
                part = fmaf(wdd[d], gg, part);
            }
            wsl[sl * 32 + h * 8 + n] = fabsf(part);
        }

        // ---- mix: adv_tot = sum_n w_final*(q-mq)*(mean_h(ws) - 1) ----
        {
            const int sl = lane >> 5, r = lane & 31;
            if (r < 8) {
                const int n = r;
                const long smp = smp0 + sl;
                const float awf = 0.25f * (wsl[sl * 32 + n] + wsl[sl * 32 + 8 + n] +
                                           wsl[sl * 32 + 16 + n] + wsl[sl * 32 + 24 + n]);
                const float adv = wfin[smp * 8 + n] *
                                  (agent_qs[smp * 8 + n] - max_q_i[smp * 8 + n]);
                float p = adv * (awf - 1.0f);
                p += __shfl_xor(p, 4, 64);   // lanes 0-7 / 32-39: xor-closed
                p += __shfl_xor(p, 2, 64);
                p += __shfl_xor(p, 1, 64);
                if (n == 0) out[smp] = p;
            }
        }
        // no barrier: hp/at/el/wsl are wave-private; same-wave LDS ops are
        // processed in order, so next group's writes can't pass these reads.
    }
}

extern "C" void kernel_launch(void* const* d_in, const int* in_sizes, int n_in,
                              void* d_out, int out_size, void* d_ws, size_t ws_size,
                              hipStream_t stream) {
    const float* agent_qs = (const float*)d_in[0];
    const float* states   = (const float*)d_in[1];
    const float* max_q_i  = (const float*)d_in[2];
    const float* hidden   = (const float*)d_in[3];
    const float* w1f = (const float*)d_in[4];
    const float* b1f = (const float*)d_in[5];
    const float* w2f = (const float*)d_in[6];
    const float* b2f = (const float*)d_in[7];
    // d_in[8..11] = w1v,b1v,w2v,b2v: v cancels in adv_q = q - mq, unused.
    const float* Wg    = (const float*)d_in[12];
    const float* att_a = (const float*)d_in[13];
    const float* Wd    = (const float*)d_in[14];
    const float* bd    = (const float*)d_in[15];
    float* out  = (float*)d_out;

    float* wfin = (float*)d_ws;                    // [BTOT][8]
    float* wdvd = wfin + (size_t)BTOT * 8;         // [BTOT][128]

    ffn_kernel<<<2048, 256, 0, stream>>>(states, w1f, b1f, w2f, b2f, Wd, bd,
                                         wfin, wdvd);
    gat_kernel<<<2048, 256, 0, stream>>>(agent_qs, max_q_i, hidden, Wg, att_a,
                                         wfin, wdvd, out);
}

// Round 4
// 331.291 us; speedup vs baseline: 1.5342x; 1.0996x over previous
//
#include <hip/hip_runtime.h>
#include <math.h>

#define STATE_DIM 168
#define BTOT 65536
#define SLS 1064   // gat per-sample hp stride (floats)
#define SPAD 184   // ffn S-tile bf16 row pitch (byte stride 368 = 16*23: b128-aligned, 2-way banks)

typedef float f32x4 __attribute__((ext_vector_type(4)));
typedef short bf16x8 __attribute__((ext_vector_type(8)));

union Frag { bf16x8 v; unsigned short u[8]; };
union Acc  { f32x4 v; float f[4]; };

__device__ __forceinline__ unsigned short f2bf(float f) {
    unsigned int u = __float_as_uint(f);
    u += 0x7fffu + ((u >> 16) & 1u);          // round-to-nearest-even
    return (unsigned short)(u >> 16);
}

// ---------------- Kernel A: hyper-net FFN via bf16 MFMA ----------------
// C[65536 x 192] = S[65536 x 168] @ [w1f | Wd], K padded to 192 (6 ksteps).
// Per block-iter: 16 samples. Wave w owns 48 cols: w1f-tile w + Wd cols 32w..32w+31.
// B-fragments hoisted to VGPRs once. Layer-2 (y1@w2f) via 2 MFMAs from LDS y1.
__global__ void __launch_bounds__(256)
ffn_kernel(const float* __restrict__ states,
           const float* __restrict__ w1f, const float* __restrict__ b1f,
           const float* __restrict__ w2f, const float* __restrict__ b2f,
           const float* __restrict__ Wd,  const float* __restrict__ bd,
           float* __restrict__ wfin, float* __restrict__ wdvd)
{
    __shared__ unsigned short S_bf[16 * SPAD];  // 5.75 KB
    __shared__ float y1[16 * 72];               // 4.5 KB, pitch 72

    const int t    = threadIdx.x;
    const int wid  = t >> 6;
    const int lane = t & 63;
    const int quad = lane >> 4;
    const int col  = lane & 15;

    // ---- hoist B fragments: B[k = ks*32+quad*8+j][c], zero for k>=168 ----
    Frag B[3][6];
    #pragma unroll
    for (int ks = 0; ks < 6; ++ks)
        #pragma unroll
        for (int j = 0; j < 8; ++j) {
            const int k = ks * 32 + quad * 8 + j;
            const bool v = (k < STATE_DIM);
            B[0][ks].u[j] = v ? f2bf(w1f[k * 64 + wid * 16 + col]) : (unsigned short)0;
            B[1][ks].u[j] = v ? f2bf(Wd[k * 128 + wid * 32 + col]) : (unsigned short)0;
            B[2][ks].u[j] = v ? f2bf(Wd[k * 128 + wid * 32 + 16 + col]) : (unsigned short)0;
        }
    Frag B2[2];
    #pragma unroll
    for (int ks = 0; ks < 2; ++ks)
        #pragma unroll
        for (int j = 0; j < 8; ++j) {
            const int k = ks * 32 + quad * 8 + j;
            B2[ks].u[j] = (col < 8) ? f2bf(w2f[k * 8 + col]) : (unsigned short)0;
        }

    const float bias1  = b1f[wid * 16 + col];
    const float biasd0 = bd[wid * 32 + col];
    const float biasd1 = bd[wid * 32 + 16 + col];
    const float bias2  = (col < 8) ? b2f[col] : 0.0f;

    for (int it = 0; it < 2; ++it) {
        const long smp0 = ((long)blockIdx.x * 2 + it) * 16;

        // ---- stage S tile (16 x 168) as bf16, zero-pad k in [168,184) ----
        {
            const int r = t >> 4, u = t & 15;
            const float* Srow = states + (smp0 + r) * STATE_DIM;
            #pragma unroll
            for (int i = 0; i < 12; ++i) {
                const int k = u + 16 * i;
                if (k < SPAD) {
                    unsigned short vv = (k < STATE_DIM) ? f2bf(Srow[k])
                                                        : (unsigned short)0;
                    S_bf[r * SPAD + k] = vv;
                }
            }
        }
        __syncthreads();

        // ---- A fragments: m = col (row of S tile), k = ks*32+quad*8+j ----
        Frag A[6];
        #pragma unroll
        for (int ks = 0; ks < 6; ++ks) {
            int k0 = ks * 32 + quad * 8;
            if (ks == 5 && quad != 0) k0 = STATE_DIM;   // read the zero pad
            A[ks].v = *(const bf16x8*)&S_bf[col * SPAD + k0];
        }

        // ---- 3 tiles x 6 ksteps MFMA ----
        Acc D0, D1, D2t;
        D0.v = (f32x4){0.f,0.f,0.f,0.f};
        D1.v = (f32x4){0.f,0.f,0.f,0.f};
        D2t.v = (f32x4){0.f,0.f,0.f,0.f};
        #pragma unroll
        for (int ks = 0; ks < 6; ++ks) {
            D0.v  = __builtin_amdgcn_mfma_f32_16x16x32_bf16(A[ks].v, B[0][ks].v, D0.v, 0, 0, 0);
            D1.v  = __builtin_amdgcn_mfma_f32_16x16x32_bf16(A[ks].v, B[1][ks].v, D1.v, 0, 0, 0);
            D2t.v = __builtin_amdgcn_mfma_f32_16x16x32_bf16(A[ks].v, B[2][ks].v, D2t.v, 0, 0, 0);
        }

        // ---- epilogue: w1f tile -> relu -> y1 LDS; Wd tiles -> global ----
        #pragma unroll
        for (int r = 0; r < 4; ++r) {
            const int m = quad * 4 + r;
            y1[m * 72 + wid * 16 + col] = fmaxf(D0.f[r] + bias1, 0.0f);
            wdvd[(smp0 + m) * 128 + wid * 32 + col]      = D1.f[r]  + biasd0;
            wdvd[(smp0 + m) * 128 + wid * 32 + 16 + col] = D2t.f[r] + biasd1;
        }
        __syncthreads();

        // ---- layer 2: wfin = |y1 @ w2f + b2f| + eps (2 MFMAs, wave0 stores) ----
        {
            Frag A2[2];
            #pragma unroll
            for (int ks = 0; ks < 2; ++ks) {
                const float4 p0 = *(const float4*)&y1[col * 72 + ks * 32 + quad * 8];
                const float4 p1 = *(const float4*)&y1[col * 72 + ks * 32 + quad * 8 + 4];
                A2[ks].u[0] = f2bf(p0.x); A2[ks].u[1] = f2bf(p0.y);
                A2[ks].u[2] = f2bf(p0.z); A2[ks].u[3] = f2bf(p0.w);
                A2[ks].u[4] = f2bf(p1.x); A2[ks].u[5] = f2bf(p1.y);
                A2[ks].u[6] = f2bf(p1.z); A2[ks].u[7] = f2bf(p1.w);
            }
            Acc Dw;
            Dw.v = (f32x4){0.f,0.f,0.f,0.f};
            Dw.v = __builtin_amdgcn_mfma_f32_16x16x32_bf16(A2[0].v, B2[0].v, Dw.v, 0, 0, 0);
            Dw.v = __builtin_amdgcn_mfma_f32_16x16x32_bf16(A2[1].v, B2[1].v, Dw.v, 0, 0, 0);
            if (wid == 0 && col < 8) {
                #pragma unroll
                for (int r = 0; r < 4; ++r)
                    wfin[(smp0 + quad * 4 + r) * 8 + col] =
                        fabsf(Dw.f[r] + bias2) + 1e-10f;
            }
        }
        __syncthreads();
    }
}

// ---------------- Kernel B: GAT via MFMA, barrier-free per-wave --------------
// (unchanged from round 3 — 108 us, correct)
__global__ void __launch_bounds__(256, 3)
gat_kernel(const float* __restrict__ agent_qs,
           const float* __restrict__ max_q_i,
           const float* __restrict__ hidden,
           const float* __restrict__ Wg,
           const float* __restrict__ att_a,
           const float* __restrict__ wfin,
           const float* __restrict__ wdvd,
           float* __restrict__ out)
{
    __shared__ float hp_lds[4][2 * SLS];
    __shared__ float attn_lds[4][544];
    __shared__ float e_lds[4][128];
    __shared__ float ws_lds[4][64];
    __shared__ float a_lds[264];

    const int t    = threadIdx.x;
    const int wid  = t >> 6;
    const int lane = t & 63;

    {
        const int h = t >> 6, r = t & 63, wch = r >> 5, d = r & 31;
        a_lds[(h * 2 + wch) * 33 + d] = att_a[t];
    }
    __syncthreads();

    float* hp  = hp_lds[wid];
    float* at  = attn_lds[wid];
    float* el  = e_lds[wid];
    float* wsl = ws_lds[wid];

    const int wgid = blockIdx.x * 4 + wid;
    const int quad = lane >> 4;
    const int col  = lane & 15;

    Frag Bf[8][2];
    #pragma unroll
    for (int tt = 0; tt < 8; ++tt)
        #pragma unroll
        for (int ks = 0; ks < 2; ++ks)
            #pragma unroll
            for (int j = 0; j < 8; ++j)
                Bf[tt][ks].u[j] =
                    f2bf(Wg[(ks * 32 + quad * 8 + j) * 128 + tt * 16 + col]);

    const int sl_a = (lane >> 3) & 1;
    const int n_a  = lane & 7;
    const int sl_w = quad >> 1;
    const int nb   = (quad & 1) * 4;

    for (int g = 0; g < 4; ++g) {
        const long smp0 = (long)wgid * 8 + 2 * g;

        Frag A0, A1;
        {
            const float* Hb = hidden + (smp0 + sl_a) * 512 + n_a * 64 + quad * 8;
            const float4 h00 = *(const float4*)(Hb);
            const float4 h01 = *(const float4*)(Hb + 4);
            const float4 h10 = *(const float4*)(Hb + 32);
            const float4 h11 = *(const float4*)(Hb + 36);
            A0.u[0] = f2bf(h00.x); A0.u[1] = f2bf(h00.y);
            A0.u[2] = f2bf(h00.z); A0.u[3] = f2bf(h00.w);
            A0.u[4] = f2bf(h01.x); A0.u[5] = f2bf(h01.y);
            A0.u[6] = f2bf(h01.z); A0.u[7] = f2bf(h01.w);
            A1.u[0] = f2bf(h10.x); A1.u[1] = f2bf(h10.y);
            A1.u[2] = f2bf(h10.z); A1.u[3] = f2bf(h10.w);
            A1.u[4] = f2bf(h11.x); A1.u[5] = f2bf(h11.y);
            A1.u[6] = f2bf(h11.z); A1.u[7] = f2bf(h11.w);
        }

        #pragma unroll
        for (int tt = 0; tt < 8; ++tt) {
            Acc acc;
            acc.v = (f32x4){0.f, 0.f, 0.f, 0.f};
            acc.v = __builtin_amdgcn_mfma_f32_16x16x32_bf16(A0.v, Bf[tt][0].v, acc.v, 0, 0, 0);
            acc.v = __builtin_amdgcn_mfma_f32_16x16x32_bf16(A1.v, Bf[tt][1].v, acc.v, 0, 0, 0);
            const int c = tt * 16 + col;
            float4 st = {acc.f[0], acc.f[1], acc.f[2], acc.f[3]};
            *(float4*)&hp[sl_w * SLS + c * 8 + ((c >> 5) << 3) + nb] = st;
        }

        {
            const int h = lane >> 4, r = lane & 15, wch = r >> 3, n = r & 7;
            const float* arow = &a_lds[(h * 2 + wch) * 33];
            #pragma unroll
            for (int sl = 0; sl < 2; ++sl) {
                float acc = 0.f;
                #pragma unroll
                for (int d = 0; d < 32; ++d)
                    acc = fmaf(hp[sl * SLS + (h * 32 + d) * 8 + h * 8 + n],
                               arow[d], acc);
                el[sl * 64 + wch * 32 + h * 8 + n] = acc;
            }
        }

        {
            const int sl = lane >> 5, r = lane & 31, h = r >> 3, i = r & 7;
            const float eiv = el[sl * 64 + h * 8 + i];
            const float* ejp = &el[sl * 64 + 32 + h * 8];
            float e[8], mx = -1e30f;
            #pragma unroll
            for (int j = 0; j < 8; ++j) {
                float v = eiv + ejp[j];
                v = v > 0.f ? v : 0.2f * v;
                e[j] = v;
                mx = fmaxf(mx, v);
            }
            float ssum = 0.f;
            #pragma unroll
            for (int j = 0; j < 8; ++j) { e[j] = __expf(e[j] - mx); ssum += e[j]; }
            const float inv = 1.f / ssum;
            #pragma unroll
            for (int j = 0; j < 8; ++j)
                at[sl * 272 + h * 66 + i * 8 + j] = e[j] * inv;
        }

        {
            const int sl = lane >> 5, r = lane & 31, h = r >> 3, n = r & 7;
            const long smp = smp0 + sl;
            float ar[8];
            #pragma unroll
            for (int j = 0; j < 8; ++j)
                ar[j] = at[sl * 272 + h * 66 + n * 8 + j];
            float wdd[32];
            {
                const float* wdp = wdvd + smp * 128 + h * 32;
                #pragma unroll
                for (int q4 = 0; q4 < 8; ++q4) {
                    const float4 v = *(const float4*)(wdp + q4 * 4);
                    wdd[q4 * 4 + 0] = v.x; wdd[q4 * 4 + 1] = v.y;
                    wdd[q4 * 4 + 2] = v.z; wdd[q4 * 4 + 3] = v.w;
                }
            }
            float part = 0.f;
            #pragma unroll
            for (int d = 0; d < 32; ++d) {
                const int c = h * 32 + d;
                const float* hb = &hp[sl * SLS + c * 8 + h * 8];
                const float4 p0 = *(const float4*)(hb);
                const float4 p1 = *(const float4*)(hb + 4);
                float gg = ar[0] * p0.x;
                gg = fmaf(ar[1], p0.y, gg);
                gg = fmaf(ar[2], p0.z, gg);
                gg = fmaf(ar[3], p0.w, gg);
                gg = fmaf(ar[4], p1.x, gg);
                gg = fmaf(ar[5], p1.y, gg);
                gg = fmaf(ar[6], p1.z, gg);
                gg = fmaf(ar[7], p1.w, gg);
                gg = gg > 0.f ? gg : (__expf(gg) - 1.0f);
                part = fmaf(wdd[d], gg, part);
            }
            wsl[sl * 32 + h * 8 + n] = fabsf(part);
        }

        {
            const int sl = lane >> 5, r = lane & 31;
            if (r < 8) {
                const int n = r;
                const long smp = smp0 + sl;
                const float awf = 0.25f * (wsl[sl * 32 + n] + wsl[sl * 32 + 8 + n] +
                                           wsl[sl * 32 + 16 + n] + wsl[sl * 32 + 24 + n]);
                const float adv = wfin[smp * 8 + n] *
                                  (agent_qs[smp * 8 + n] - max_q_i[smp * 8 + n]);
                float p = adv * (awf - 1.0f);
                p += __shfl_xor(p, 4, 64);
                p += __shfl_xor(p, 2, 64);
                p += __shfl_xor(p, 1, 64);
                if (n == 0) out[smp] = p;
            }
        }
    }
}

extern "C" void kernel_launch(void* const* d_in, const int* in_sizes, int n_in,
                              void* d_out, int out_size, void* d_ws, size_t ws_size,
                              hipStream_t stream) {
    const float* agent_qs = (const float*)d_in[0];
    const float* states   = (const float*)d_in[1];
    const float* max_q_i  = (const float*)d_in[2];
    const float* hidden   = (const float*)d_in[3];
    const float* w1f = (const float*)d_in[4];
    const float* b1f = (const float*)d_in[5];
    const float* w2f = (const float*)d_in[6];
    const float* b2f = (const float*)d_in[7];
    // d_in[8..11] = w1v,b1v,w2v,b2v: v cancels in adv_q = q - mq, unused.
    const float* Wg    = (const float*)d_in[12];
    const float* att_a = (const float*)d_in[13];
    const float* Wd    = (const float*)d_in[14];
    const float* bd    = (const float*)d_in[15];
    float* out  = (float*)d_out;

    float* wfin = (float*)d_ws;                    // [BTOT][8]
    float* wdvd = wfin + (size_t)BTOT * 8;         // [BTOT][128]

    ffn_kernel<<<2048, 256, 0, stream>>>(states, w1f, b1f, w2f, b2f, Wd, bd,
                                         wfin, wdvd);
    gat_kernel<<<2048, 256, 0, stream>>>(agent_qs, max_q_i, hidden, Wg, att_a,
                                         wfin, wdvd, out);
}